// Round 10
// baseline (161.657 us; speedup 1.0000x reference)
//
#include <hip/hip_runtime.h>
#include <stdint.h>

typedef uint32_t u32;
typedef uint64_t u64;

#define NB 4
#define NA 9
#define NH 34
#define NW 60
#define HW (NH*NW)            // 2040
#define NBOX (NA*HW)          // 18360
#define PRE_NMS 3000
#define POST_NMS 300
#define NBUCKET 4096
#define SEGCAP 4096
#define NTH 1024
#define PER 18                // 18*1024 = 18432 >= 18360
#define NCAND 1088            // bit-matrix coverage (examined ~1091 measured)
#define MWc 17                // words per mask row (1088/64)
#define NCHK 17               // 64-candidate chunks

// Anchor widths/heights (f64->f32 roundings, matching np.array(..., float32)).
__device__ __constant__ float c_aw[9] = {
  45.254833995939045f, 64.0f,  90.50966799187808f,
  90.50966799187808f,  128.0f, 181.01933598375617f,
  181.01933598375617f, 256.0f, 362.03867196751233f };
__device__ __constant__ float c_ah[9] = {
  90.50966799187808f,  64.0f,  45.254833995939045f,
  181.01933598375617f, 128.0f, 90.50966799187808f,
  362.03867196751233f, 256.0f, 181.01933598375617f };

__device__ __forceinline__ u64 readlane64(u64 v, int lane) {
  u32 lo = __builtin_amdgcn_readlane((u32)(v & 0xffffffffull), lane);
  u32 hi = __builtin_amdgcn_readlane((u32)(v >> 32), lane);
  return ((u64)hi << 32) | lo;
}

__device__ __forceinline__ float4 decode_box(const float* __restrict__ dl, int idx) {
  int a = idx / HW;
  int r = idx - a * HW;
  int h = r / NW;
  int w = r - h * NW;
  const float* dp = dl + (4 * a) * HW + r;
  float tx = dp[0];
  float ty = dp[HW];
  float tw = dp[2 * HW];
  float th = dp[3 * HW];
  float aw = c_aw[a], ah = c_ah[a];
  float ctr_x = ((float)w + 0.5f) * 16.0f + tx * aw;
  float ctr_y = ((float)h + 0.5f) * 16.0f + ty * ah;
  float w1 = expf(tw) * aw;
  float h1 = expf(th) * ah;
  float x1 = ctr_x - 0.5f * w1;
  float y1 = ctr_y - 0.5f * h1;
  float x2 = x1 + w1;
  float y2 = y1 + h1;
  x1 = fminf(fmaxf(x1, 0.0f), 959.0f);
  x2 = fminf(fmaxf(x2, 0.0f), 959.0f);
  y1 = fminf(fmaxf(y1, 0.0f), 543.0f);
  y2 = fminf(fmaxf(y2, 0.0f), 543.0f);
  return make_float4(x1, y1, x2, y2);
}

// ---------------------------------------------------------------------------
// K1 v3: sort-free exact ranking; single-wave suffix scan (no 20-barrier
// block scan). Ranking/scatter logic identical to rounds 4-8 (verified).
// ---------------------------------------------------------------------------
__global__ void __launch_bounds__(NTH)
topk_rank_decode_kernel(const float* __restrict__ scores,
                        const float* __restrict__ deltas,
                        float4* __restrict__ boxes_ws)
{
  __shared__ u32 s_base[NBUCKET];
  __shared__ u32 s_cnt[NBUCKET];
  __shared__ u64 s_keys[SEGCAP];
  __shared__ u32 s_sfx[NTH];

  const int tid = threadIdx.x;
  const int b   = blockIdx.x;
  const float* sc = scores + b * NBOX;

  for (int t = tid; t < NBUCKET; t += NTH) s_cnt[t] = 0;
  __syncthreads();

  // histogram
  for (int m = 0; m < PER; ++m) {
    int i = tid + m * NTH;
    if (i < NBOX) {
      float s = sc[i];
      int bk = (int)(s * (float)NBUCKET);
      bk = bk < 0 ? 0 : (bk > NBUCKET - 1 ? NBUCKET - 1 : bk);
      atomicAdd(&s_cnt[bk], 1u);
    }
  }
  __syncthreads();

  // group-of-4 sums; inclusive suffix scan done by wave 0 only (16 elem/lane)
  u32 h0 = s_cnt[4*tid], h1 = s_cnt[4*tid+1], h2 = s_cnt[4*tid+2], h3 = s_cnt[4*tid+3];
  s_sfx[tid] = h0 + h1 + h2 + h3;
  __syncthreads();
  if (tid < 64) {
    const int l = tid;
    u32 v0,v1,v2,v3,v4,v5,v6,v7,v8,v9,v10,v11,v12,v13,v14,v15;
    {
      const u32* p = &s_sfx[l * 16];
      v0=p[0]; v1=p[1]; v2=p[2]; v3=p[3]; v4=p[4]; v5=p[5]; v6=p[6]; v7=p[7];
      v8=p[8]; v9=p[9]; v10=p[10]; v11=p[11]; v12=p[12]; v13=p[13]; v14=p[14]; v15=p[15];
    }
    v14+=v15; v13+=v14; v12+=v13; v11+=v12; v10+=v11; v9+=v10; v8+=v9; v7+=v8;
    v6+=v7; v5+=v6; v4+=v5; v3+=v4; v2+=v3; v1+=v2; v0+=v1;
    u32 tot = v0;
    u32 inc = tot;
    #pragma unroll
    for (int off = 1; off < 64; off <<= 1) {
      u32 x = (u32)__shfl_down((int)inc, off, 64);
      if (l + off < 64) inc += x;
    }
    u32 exc = inc - tot;
    {
      u32* p = &s_sfx[l * 16];
      p[0]=v0+exc; p[1]=v1+exc; p[2]=v2+exc; p[3]=v3+exc;
      p[4]=v4+exc; p[5]=v5+exc; p[6]=v6+exc; p[7]=v7+exc;
      p[8]=v8+exc; p[9]=v9+exc; p[10]=v10+exc; p[11]=v11+exc;
      p[12]=v12+exc; p[13]=v13+exc; p[14]=v14+exc; p[15]=v15+exc;
    }
  }
  __syncthreads();

  // per-bucket base = #elements in strictly higher buckets
  {
    u32 Gn = (tid < NTH - 1) ? s_sfx[tid + 1] : 0u;
    s_base[4*tid+3] = Gn;
    s_base[4*tid+2] = Gn + h3;
    s_base[4*tid+1] = Gn + h3 + h2;
    s_base[4*tid+0] = Gn + h3 + h2 + h1;
  }
  __syncthreads();

  for (int t = tid; t < NBUCKET; t += NTH) s_cnt[t] = 0;
  for (int t = tid; t < SEGCAP; t += NTH) s_keys[t] = 0ull;
  __syncthreads();

  // scatter candidates of buckets with base < 3000 into their segment
  for (int m = 0; m < PER; ++m) {
    int i = tid + m * NTH;
    if (i < NBOX) {
      float s = sc[i];
      int bk = (int)(s * (float)NBUCKET);
      bk = bk < 0 ? 0 : (bk > NBUCKET - 1 ? NBUCKET - 1 : bk);
      u32 base = s_base[bk];
      if (base < PRE_NMS) {
        u32 loc = atomicAdd(&s_cnt[bk], 1u);
        u32 pos = base + loc;
        if (pos < SEGCAP) {
          u64 key = ((u64)__float_as_uint(s) << 32) | (u32)(~(u32)i);
          s_keys[pos] = key;
        }
      }
    }
  }
  __syncthreads();

  // exact rank via bucket-peer scan; decode winners straight to rank slot
  const float* dl = deltas + b * (4 * NA * HW);
  for (int m = 0; m < SEGCAP / NTH; ++m) {
    int p = tid + m * NTH;
    u64 key = s_keys[p];
    float s = __uint_as_float((u32)(key >> 32));
    int bk = (int)(s * (float)NBUCKET);
    bk = bk < 0 ? 0 : (bk > NBUCKET - 1 ? NBUCKET - 1 : bk);
    u32 base = s_base[bk];
    u32 cnt  = s_cnt[bk];
    u32 local = 0;
    for (u32 q = base; q < base + cnt; ++q)
      local += (s_keys[q] > key) ? 1u : 0u;
    u32 R = base + local;
    if (key != 0ull && R < PRE_NMS) {
      int idx = (int)(~(u32)key);
      boxes_ws[b * PRE_NMS + R] = decode_box(dl, idx);
    }
  }
}

// ---------------------------------------------------------------------------
// K2 v4: 1088x1088 suppression matrix. masks2[b][row][w], w<17.
// ---------------------------------------------------------------------------
__global__ void __launch_bounds__(256)
mask_corner_kernel(const float4* __restrict__ boxes_ws, u64* __restrict__ masks2)
{
  const int wq = blockIdx.x;          // word 0..16
  const int rb = blockIdx.y;          // row block 0..4
  const int b  = blockIdx.z;
  const int tid = threadIdx.x;
  __shared__ float4 s_cb[64];
  __shared__ float  s_ca[64];
  if (tid < 64) {
    int j = wq * 64 + tid;            // < 1088 < PRE_NMS
    float4 v = boxes_ws[b * PRE_NMS + j];
    s_cb[tid] = v;
    s_ca[tid] = (v.z - v.x) * (v.w - v.y);
  }
  __syncthreads();
  int row = rb * 256 + tid;
  if (row < NCAND) {
    float4 r = boxes_ws[b * PRE_NMS + row];
    float ra = (r.z - r.x) * (r.w - r.y);
    u64 word = 0;
    #pragma unroll
    for (int k = 0; k < 64; ++k) {
      float4 cb = s_cb[k];
      float iw = fminf(r.z, cb.z) - fmaxf(r.x, cb.x);
      float ih = fminf(r.w, cb.w) - fmaxf(r.y, cb.y);
      iw = fmaxf(iw, 0.0f);
      ih = fmaxf(ih, 0.0f);
      float inter = iw * ih;
      float uni = ra + s_ca[k] - inter;
      word |= ((u64)(inter > 0.7f * fmaxf(uni, 1e-8f))) << k;
    }
    masks2[((size_t)b * NCAND + row) * MWc + wq] = word;
  }
}

// ---------------------------------------------------------------------------
// K3 v10: producer/consumer wave-specialized kept-bitmap greedy reduce.
// 128 threads. Wave 1 stages chunk j+1's 64x17-word row block (8.7 KB,
// coalesced) from global into a ping-pong LDS buffer while wave 0 processes
// chunk j from LDS (concurrent waves on one CU — m114). One barrier per
// chunk. LDS total ~19 KB (round 9's 148 KB static LDS exceeded the 64 KB
// workgroup limit => kernel never launched => absmax 960).
// Per chunk (wave 0): lane m reads its 17 row words + 17 broadcast kept-bm
// words from LDS, one ballot, short SALU chain with readlane64 of the
// diagonal word. No local arrays, no runtime register-array indexing
// (rounds 4-8: those always went to scratch).
// Exact greedy; phase C fallback covers candidates >= 1088 (~3 iters here).
// ---------------------------------------------------------------------------
__global__ void __launch_bounds__(128)
nms_reduce_kernel(const float4* __restrict__ boxes_ws,
                  const u64* __restrict__ masks2,
                  float* __restrict__ out)
{
  const int b = blockIdx.x;
  const int tid = threadIdx.x;
  const int wv = tid >> 6;          // 0 = consumer, 1 = stager
  const int lane = tid & 63;

  __shared__ __align__(16) u64 s_buf[2][64 * MWc];   // 2 x 8704 B
  __shared__ u64 s_bm[MWc];
  __shared__ u32 s_kept[POST_NMS];
  __shared__ u32 s_nk;

  const u64* mbase = masks2 + (size_t)b * NCAND * MWc;

  // init: wave 1 stages chunk 0; wave 0 zeroes the kept bitmap
  if (wv == 1) {
    #pragma unroll
    for (int w = 0; w < MWc; ++w)
      s_buf[0][lane + w * 64] = mbase[lane + w * 64];
  } else if (lane < MWc) {
    s_bm[lane] = 0ull;
  }
  __syncthreads();

  int nk = 0;
  bool fin = false;

  for (int chunk = 0; chunk < NCHK; ++chunk) {
    if (wv == 1) {
      // stage chunk+1 into the other buffer (concurrent with wave 0)
      if (chunk + 1 < NCHK) {
        const u64* src = mbase + (size_t)(chunk + 1) * 64 * MWc;
        u64* dst = s_buf[(chunk + 1) & 1];
        #pragma unroll
        for (int w = 0; w < MWc; ++w)
          dst[lane + w * 64] = src[lane + w * 64];
      }
    } else if (!fin) {
      const u64* row = &s_buf[chunk & 1][lane * MWc];
      u64 s = 0ull;
      #pragma unroll
      for (int w = 0; w < MWc; ++w)
        s |= row[w] & s_bm[w];
      u64 D = row[chunk];             // intra-chunk suppression bits
      u64 a = __ballot(s == 0ull);
      u64 supw = 0ull, keepm = 0ull;
      while (a) {
        int k = __ffsll((unsigned long long)a) - 1;
        a &= a - 1ull;
        if (!((supw >> k) & 1ull)) {
          keepm |= 1ull << k;
          if (lane == 0) s_kept[nk] = (u32)(chunk * 64 + k);
          ++nk;
          if (nk >= POST_NMS) { fin = true; break; }
          supw |= readlane64(D, k);
        }
      }
      if (lane == 0) s_bm[chunk] = keepm;
    }
    __syncthreads();
  }

  // ---- phase C (wave 0 only): exact fallback past candidate NCAND ----
  if (wv == 0) {
    if (nk < POST_NMS) {
      float4 kb[5];
      float  ka[5];
      #pragma unroll
      for (int s = 0; s < 5; ++s) {
        int t = s * 64 + lane;
        float4 v = make_float4(0.f, 0.f, 0.f, 0.f);
        if (t < nk) v = boxes_ws[b * PRE_NMS + s_kept[t]];
        kb[s] = v;
        ka[s] = (v.z - v.x) * (v.w - v.y);
      }
      for (int i = NCAND; i < PRE_NMS; ++i) {
        if (nk >= POST_NMS) break;
        float4 c = boxes_ws[b * PRE_NMS + i];
        float carea = (c.z - c.x) * (c.w - c.y);
        bool over = false;
        #pragma unroll
        for (int s = 0; s < 5; ++s) {
          if (s * 64 < nk) {
            if (s * 64 + lane < nk) {
              float iw = fminf(kb[s].z, c.z) - fmaxf(kb[s].x, c.x);
              float ih = fminf(kb[s].w, c.w) - fmaxf(kb[s].y, c.y);
              iw = fmaxf(iw, 0.0f);
              ih = fmaxf(ih, 0.0f);
              float inter = iw * ih;
              float uni = ka[s] + carea - inter;
              over = over || (inter > 0.7f * fmaxf(uni, 1e-8f));
            }
          }
        }
        if (__ballot((int)over) == 0ull) {
          int s = nk >> 6, l = nk & 63;
          #pragma unroll
          for (int q = 0; q < 5; ++q)
            if (q == s && lane == l) { kb[q] = c; ka[q] = carea; }
          if (lane == 0) s_kept[nk] = (u32)i;
          ++nk;
        }
      }
    }
    if (lane == 0) s_nk = (u32)nk;
  }
  __syncthreads();

  // ---- emit: first nk kept (score order), zero-pad to 300 ----
  u32 fnk = s_nk;
  float4* outv = (float4*)out;
  for (int t = tid; t < POST_NMS; t += 128) {
    float4 v = make_float4(0.f, 0.f, 0.f, 0.f);
    if ((u32)t < fnk) v = boxes_ws[b * PRE_NMS + s_kept[t]];
    outv[b * POST_NMS + t] = v;
  }
}

// ---------------------------------------------------------------------------
// Fallback: round-1 monolithic kernel (verified) if ws is too small.
// ---------------------------------------------------------------------------
__global__ void __launch_bounds__(NTH)
rpn_proposal_mono(const float* __restrict__ scores,
                  const float* __restrict__ deltas,
                  float* __restrict__ out)
{
  __shared__ __align__(16) char smem[16384 + 32768 + 4096];
  u32* s_hist = (u32*)smem;
  u64* s_cand = (u64*)(smem + 16384);
  u32* s_sfx  = (u32*)(smem + 16384 + 32768);
  float4* s_box = (float4*)smem;
  __shared__ u32 s_kept[POST_NMS];
  __shared__ u32 s_meta[4];

  const int tid = threadIdx.x;
  const int b   = blockIdx.x;
  const float* sc = scores + b * NBOX;

  for (int t = tid; t < NBUCKET; t += NTH) s_hist[t] = 0;
  if (tid < 4) s_meta[tid] = 0;
  __syncthreads();
  for (int m = 0; m < PER; ++m) {
    int i = tid + m * NTH;
    if (i < NBOX) {
      float s = sc[i];
      int bk = (int)(s * (float)NBUCKET);
      bk = bk < 0 ? 0 : (bk > NBUCKET - 1 ? NBUCKET - 1 : bk);
      atomicAdd(&s_hist[bk], 1u);
    }
  }
  __syncthreads();
  {
    u32 g = s_hist[4*tid] + s_hist[4*tid+1] + s_hist[4*tid+2] + s_hist[4*tid+3];
    s_sfx[tid] = g;
  }
  __syncthreads();
  for (int d = 1; d < NTH; d <<= 1) {
    u32 v = (tid + d < NTH) ? s_sfx[tid + d] : 0u;
    __syncthreads();
    s_sfx[tid] += v;
    __syncthreads();
  }
  {
    u32 sg  = s_sfx[tid];
    u32 sgn = (tid < NTH - 1) ? s_sfx[tid + 1] : 0u;
    if (sg >= PRE_NMS && sgn < PRE_NMS) {
      u32 c = sgn;
      for (int t = 4 * tid + 3; t >= 4 * tid; --t) {
        c += s_hist[t];
        if (c >= PRE_NMS) { s_meta[0] = (u32)t; s_meta[1] = c; break; }
      }
    }
  }
  __syncthreads();
  const u32 T = s_meta[0];
  for (int m = 0; m < PER; ++m) {
    int i = tid + m * NTH;
    if (i < NBOX) {
      float s = sc[i];
      int bk = (int)(s * (float)NBUCKET);
      bk = bk < 0 ? 0 : (bk > NBUCKET - 1 ? NBUCKET - 1 : bk);
      if ((u32)bk >= T) {
        u32 pos = atomicAdd(&s_meta[2], 1u);
        if (pos < SEGCAP) {
          u64 key = ((u64)__float_as_uint(s) << 32) | (u32)(~(u32)i);
          s_cand[pos] = key;
        }
      }
    }
  }
  __syncthreads();
  {
    u32 C = s_meta[2]; if (C > SEGCAP) C = SEGCAP;
    for (u32 p = C + tid; p < SEGCAP; p += NTH) s_cand[p] = 0ull;
  }
  for (int kk = 2; kk <= SEGCAP; kk <<= 1) {
    for (int j = kk >> 1; j > 0; j >>= 1) {
      __syncthreads();
      #pragma unroll
      for (int m = 0; m < 2; ++m) {
        int t = tid + m * NTH;
        int i = ((t & ~(j - 1)) << 1) | (t & (j - 1));
        int p = i | j;
        u64 a  = s_cand[i];
        u64 bb = s_cand[p];
        bool desc = (i & kk) == 0;
        bool sw = desc ? (a < bb) : (a > bb);
        if (sw) { s_cand[i] = bb; s_cand[p] = a; }
      }
    }
  }
  __syncthreads();
  const float* dl = deltas + b * (4 * NA * HW);
  float4 bx[3];
  #pragma unroll
  for (int m = 0; m < 3; ++m) {
    int k = tid + m * NTH;
    if (k < PRE_NMS) {
      u64 key = s_cand[k];
      bx[m] = decode_box(dl, (int)(~(u32)key));
    }
  }
  __syncthreads();
  #pragma unroll
  for (int m = 0; m < 3; ++m) {
    int k = tid + m * NTH;
    if (k < PRE_NMS) s_box[k] = bx[m];
  }
  __syncthreads();
  if (tid < 64) {
    const int lane = tid;
    float4 kb[5];
    float  ka[5];
    int nk = 0;
    for (int i = 0; i < PRE_NMS; ++i) {
      if (nk >= POST_NMS) break;
      float4 c = s_box[i];
      float carea = (c.z - c.x) * (c.w - c.y);
      bool over = false;
      #pragma unroll
      for (int s = 0; s < 5; ++s) {
        if (s * 64 < nk) {
          if (s * 64 + lane < nk) {
            float iw = fminf(kb[s].z, c.z) - fmaxf(kb[s].x, c.x);
            float ih = fminf(kb[s].w, c.w) - fmaxf(kb[s].y, c.y);
            iw = fmaxf(iw, 0.0f);
            ih = fmaxf(ih, 0.0f);
            float inter = iw * ih;
            float uni = ka[s] + carea - inter;
            over = over || (inter > 0.7f * fmaxf(uni, 1e-8f));
          }
        }
      }
      if (__ballot((int)over) == 0ull) {
        int s = nk >> 6, l = nk & 63;
        #pragma unroll
        for (int q = 0; q < 5; ++q)
          if (q == s && lane == l) { kb[q] = c; ka[q] = carea; }
        if (lane == 0) s_kept[nk] = (u32)i;
        ++nk;
      }
    }
    if (lane == 0) s_meta[3] = (u32)nk;
  }
  __syncthreads();
  if (tid < POST_NMS) {
    u32 nk = s_meta[3];
    float4 v = make_float4(0.0f, 0.0f, 0.0f, 0.0f);
    if ((u32)tid < nk) v = s_box[s_kept[tid]];
    ((float4*)out)[b * POST_NMS + tid] = v;
  }
}

extern "C" void kernel_launch(void* const* d_in, const int* in_sizes, int n_in,
                              void* d_out, int out_size, void* d_ws, size_t ws_size,
                              hipStream_t stream) {
  const float* scores = (const float*)d_in[0];
  const float* deltas = (const float*)d_in[1];
  (void)in_sizes; (void)n_in; (void)out_size;

  const size_t mask_off   = 196608;                                   // 192KB aligned
  const size_t mask_bytes = (size_t)NB * NCAND * MWc * sizeof(u64);   // ~592 KB
  const size_t need       = mask_off + mask_bytes;

  if (ws_size >= need) {
    float4* boxes_ws = (float4*)d_ws;
    u64*    masks2   = (u64*)((char*)d_ws + mask_off);
    topk_rank_decode_kernel<<<dim3(NB), dim3(NTH), 0, stream>>>(scores, deltas, boxes_ws);
    mask_corner_kernel<<<dim3(MWc, (NCAND + 255) / 256, NB), dim3(256), 0, stream>>>(boxes_ws, masks2);
    nms_reduce_kernel<<<dim3(NB), dim3(128), 0, stream>>>(boxes_ws, masks2, (float*)d_out);
  } else {
    rpn_proposal_mono<<<dim3(NB), dim3(NTH), 0, stream>>>(scores, deltas, (float*)d_out);
  }
}

// Round 11
// 146.043 us; speedup vs baseline: 1.1069x; 1.1069x over previous
//
#include <hip/hip_runtime.h>
#include <stdint.h>

typedef uint32_t u32;
typedef uint64_t u64;

#define NB 4
#define NA 9
#define NH 34
#define NW 60
#define HW (NH*NW)            // 2040
#define NBOX (NA*HW)          // 18360
#define PRE_NMS 3000
#define POST_NMS 300
#define NBUCKET 4096
#define SEGCAP 4096
#define NTH 1024
#define PER 18                // 18*1024 = 18432 >= 18360
#define NCAND 2048            // bit-matrix coverage (examined ~1050 measured)
#define MWT 32                // words per candidate (2048/64)

// Anchor widths/heights (f64->f32 roundings, matching np.array(..., float32)).
__device__ __constant__ float c_aw[9] = {
  45.254833995939045f, 64.0f,  90.50966799187808f,
  90.50966799187808f,  128.0f, 181.01933598375617f,
  181.01933598375617f, 256.0f, 362.03867196751233f };
__device__ __constant__ float c_ah[9] = {
  90.50966799187808f,  64.0f,  45.254833995939045f,
  181.01933598375617f, 128.0f, 90.50966799187808f,
  362.03867196751233f, 256.0f, 181.01933598375617f };

__device__ __forceinline__ u64 readlane64(u64 v, int lane) {
  u32 lo = __builtin_amdgcn_readlane((u32)(v & 0xffffffffull), lane);
  u32 hi = __builtin_amdgcn_readlane((u32)(v >> 32), lane);
  return ((u64)hi << 32) | lo;
}

__device__ __forceinline__ float4 decode_box(const float* __restrict__ dl, int idx) {
  int a = idx / HW;
  int r = idx - a * HW;
  int h = r / NW;
  int w = r - h * NW;
  const float* dp = dl + (4 * a) * HW + r;
  float tx = dp[0];
  float ty = dp[HW];
  float tw = dp[2 * HW];
  float th = dp[3 * HW];
  float aw = c_aw[a], ah = c_ah[a];
  float ctr_x = ((float)w + 0.5f) * 16.0f + tx * aw;
  float ctr_y = ((float)h + 0.5f) * 16.0f + ty * ah;
  float w1 = expf(tw) * aw;
  float h1 = expf(th) * ah;
  float x1 = ctr_x - 0.5f * w1;
  float y1 = ctr_y - 0.5f * h1;
  float x2 = x1 + w1;
  float y2 = y1 + h1;
  x1 = fminf(fmaxf(x1, 0.0f), 959.0f);
  x2 = fminf(fmaxf(x2, 0.0f), 959.0f);
  y1 = fminf(fmaxf(y1, 0.0f), 543.0f);
  y2 = fminf(fmaxf(y2, 0.0f), 543.0f);
  return make_float4(x1, y1, x2, y2);
}

// ---------------------------------------------------------------------------
// K1 v3: sort-free exact ranking; single-wave suffix scan. (Verified r10.)
// ---------------------------------------------------------------------------
__global__ void __launch_bounds__(NTH)
topk_rank_decode_kernel(const float* __restrict__ scores,
                        const float* __restrict__ deltas,
                        float4* __restrict__ boxes_ws)
{
  __shared__ u32 s_base[NBUCKET];
  __shared__ u32 s_cnt[NBUCKET];
  __shared__ u64 s_keys[SEGCAP];
  __shared__ u32 s_sfx[NTH];

  const int tid = threadIdx.x;
  const int b   = blockIdx.x;
  const float* sc = scores + b * NBOX;

  for (int t = tid; t < NBUCKET; t += NTH) s_cnt[t] = 0;
  __syncthreads();

  for (int m = 0; m < PER; ++m) {
    int i = tid + m * NTH;
    if (i < NBOX) {
      float s = sc[i];
      int bk = (int)(s * (float)NBUCKET);
      bk = bk < 0 ? 0 : (bk > NBUCKET - 1 ? NBUCKET - 1 : bk);
      atomicAdd(&s_cnt[bk], 1u);
    }
  }
  __syncthreads();

  u32 h0 = s_cnt[4*tid], h1 = s_cnt[4*tid+1], h2 = s_cnt[4*tid+2], h3 = s_cnt[4*tid+3];
  s_sfx[tid] = h0 + h1 + h2 + h3;
  __syncthreads();
  if (tid < 64) {
    const int l = tid;
    u32 v0,v1,v2,v3,v4,v5,v6,v7,v8,v9,v10,v11,v12,v13,v14,v15;
    {
      const u32* p = &s_sfx[l * 16];
      v0=p[0]; v1=p[1]; v2=p[2]; v3=p[3]; v4=p[4]; v5=p[5]; v6=p[6]; v7=p[7];
      v8=p[8]; v9=p[9]; v10=p[10]; v11=p[11]; v12=p[12]; v13=p[13]; v14=p[14]; v15=p[15];
    }
    v14+=v15; v13+=v14; v12+=v13; v11+=v12; v10+=v11; v9+=v10; v8+=v9; v7+=v8;
    v6+=v7; v5+=v6; v4+=v5; v3+=v4; v2+=v3; v1+=v2; v0+=v1;
    u32 tot = v0;
    u32 inc = tot;
    #pragma unroll
    for (int off = 1; off < 64; off <<= 1) {
      u32 x = (u32)__shfl_down((int)inc, off, 64);
      if (l + off < 64) inc += x;
    }
    u32 exc = inc - tot;
    {
      u32* p = &s_sfx[l * 16];
      p[0]=v0+exc; p[1]=v1+exc; p[2]=v2+exc; p[3]=v3+exc;
      p[4]=v4+exc; p[5]=v5+exc; p[6]=v6+exc; p[7]=v7+exc;
      p[8]=v8+exc; p[9]=v9+exc; p[10]=v10+exc; p[11]=v11+exc;
      p[12]=v12+exc; p[13]=v13+exc; p[14]=v14+exc; p[15]=v15+exc;
    }
  }
  __syncthreads();

  {
    u32 Gn = (tid < NTH - 1) ? s_sfx[tid + 1] : 0u;
    s_base[4*tid+3] = Gn;
    s_base[4*tid+2] = Gn + h3;
    s_base[4*tid+1] = Gn + h3 + h2;
    s_base[4*tid+0] = Gn + h3 + h2 + h1;
  }
  __syncthreads();

  for (int t = tid; t < NBUCKET; t += NTH) s_cnt[t] = 0;
  for (int t = tid; t < SEGCAP; t += NTH) s_keys[t] = 0ull;
  __syncthreads();

  for (int m = 0; m < PER; ++m) {
    int i = tid + m * NTH;
    if (i < NBOX) {
      float s = sc[i];
      int bk = (int)(s * (float)NBUCKET);
      bk = bk < 0 ? 0 : (bk > NBUCKET - 1 ? NBUCKET - 1 : bk);
      u32 base = s_base[bk];
      if (base < PRE_NMS) {
        u32 loc = atomicAdd(&s_cnt[bk], 1u);
        u32 pos = base + loc;
        if (pos < SEGCAP) {
          u64 key = ((u64)__float_as_uint(s) << 32) | (u32)(~(u32)i);
          s_keys[pos] = key;
        }
      }
    }
  }
  __syncthreads();

  const float* dl = deltas + b * (4 * NA * HW);
  for (int m = 0; m < SEGCAP / NTH; ++m) {
    int p = tid + m * NTH;
    u64 key = s_keys[p];
    float s = __uint_as_float((u32)(key >> 32));
    int bk = (int)(s * (float)NBUCKET);
    bk = bk < 0 ? 0 : (bk > NBUCKET - 1 ? NBUCKET - 1 : bk);
    u32 base = s_base[bk];
    u32 cnt  = s_cnt[bk];
    u32 local = 0;
    for (u32 q = base; q < base + cnt; ++q)
      local += (s_keys[q] > key) ? 1u : 0u;
    u32 R = base + local;
    if (key != 0ull && R < PRE_NMS) {
      int idx = (int)(~(u32)key);
      boxes_ws[b * PRE_NMS + R] = decode_box(dl, idx);
    }
  }
}

// ---------------------------------------------------------------------------
// K2 v5: COLUMN-MAJOR 2048x2048 suppression matrix, lower triangle only.
// masksT[(b*32 + w)*2048 + c] = supp bits of candidate c vs cands 64w..64w+63.
// Writes coalesced in c. Blocks with wq > 4*rb+3 hold no needed words (w*64
// must be <= c) and exit; K3 masks unwritten words with bm[w]==0.
// ---------------------------------------------------------------------------
__global__ void __launch_bounds__(256)
mask_kernel_T(const float4* __restrict__ boxes_ws, u64* __restrict__ masksT)
{
  const int wq = blockIdx.x;          // word 0..31
  const int rb = blockIdx.y;          // candidate block 0..7
  const int b  = blockIdx.z;
  if (wq > 4 * rb + 3) return;        // triangle
  const int tid = threadIdx.x;
  __shared__ float4 s_cb[64];
  __shared__ float  s_ca[64];
  if (tid < 64) {
    int j = wq * 64 + tid;            // < 2048 < PRE_NMS
    float4 v = boxes_ws[b * PRE_NMS + j];
    s_cb[tid] = v;
    s_ca[tid] = (v.z - v.x) * (v.w - v.y);
  }
  __syncthreads();
  int c = rb * 256 + tid;             // < 2048
  float4 r = boxes_ws[b * PRE_NMS + c];
  float ra = (r.z - r.x) * (r.w - r.y);
  u64 word = 0;
  #pragma unroll
  for (int k = 0; k < 64; ++k) {
    float4 cb = s_cb[k];
    float iw = fminf(r.z, cb.z) - fmaxf(r.x, cb.x);
    float ih = fminf(r.w, cb.w) - fmaxf(r.y, cb.y);
    iw = fmaxf(iw, 0.0f);
    ih = fmaxf(ih, 0.0f);
    float inter = iw * ih;
    float uni = ra + s_ca[k] - inter;
    word |= ((u64)(inter > 0.7f * fmaxf(uni, 1e-8f))) << k;
  }
  masksT[((size_t)b * MWT + wq) * NCAND + c] = word;
}

// ---------------------------------------------------------------------------
// K3 v11: single-wave, barrier-free, column-major direct-load chain.
// Per 64-chunk j: 32 fixed named u64 loads (lane-coalesced; words w>j are
// garbage but masked by bm[w]==0) + 1 diagonal-word load (runtime ADDRESS,
// never a runtime register index) -> one vmcnt drain -> fully static
// s=(v0&bm[0])|...|(v31&bm[31]) -> ballot -> verified SALU keep chain.
// No LDS staging, no producer wave (round 10: per-chunk barriered streaming
// cost ~8K cyc/chunk), no local arrays (rounds 4-8: scratch demotion).
// Exact greedy; phase C fallback covers candidates >= 2048 (unreached at
// measured examined ~1050).
// ---------------------------------------------------------------------------
__global__ void __launch_bounds__(64)
nms_reduce_kernel(const float4* __restrict__ boxes_ws,
                  const u64* __restrict__ masksT,
                  float* __restrict__ out)
{
  const int b = blockIdx.x;
  const int lane = threadIdx.x;
  __shared__ u64 s_bm[MWT];
  __shared__ u32 s_kept[POST_NMS];

  const u64* mtb = masksT + (size_t)b * MWT * NCAND;

  if (lane < MWT) s_bm[lane] = 0ull;
  __syncthreads();

  int nk = 0;
  bool fin = false;

  for (int j = 0; j < MWT && !fin; ++j) {
    const int c = j * 64 + lane;
    const u64* pc = mtb + c;
    // 33 independent coalesced loads, then one drain
    u64 v0  = pc[ 0*NCAND], v1  = pc[ 1*NCAND], v2  = pc[ 2*NCAND], v3  = pc[ 3*NCAND];
    u64 v4  = pc[ 4*NCAND], v5  = pc[ 5*NCAND], v6  = pc[ 6*NCAND], v7  = pc[ 7*NCAND];
    u64 v8  = pc[ 8*NCAND], v9  = pc[ 9*NCAND], v10 = pc[10*NCAND], v11 = pc[11*NCAND];
    u64 v12 = pc[12*NCAND], v13 = pc[13*NCAND], v14 = pc[14*NCAND], v15 = pc[15*NCAND];
    u64 v16 = pc[16*NCAND], v17 = pc[17*NCAND], v18 = pc[18*NCAND], v19 = pc[19*NCAND];
    u64 v20 = pc[20*NCAND], v21 = pc[21*NCAND], v22 = pc[22*NCAND], v23 = pc[23*NCAND];
    u64 v24 = pc[24*NCAND], v25 = pc[25*NCAND], v26 = pc[26*NCAND], v27 = pc[27*NCAND];
    u64 v28 = pc[28*NCAND], v29 = pc[29*NCAND], v30 = pc[30*NCAND], v31 = pc[31*NCAND];
    u64 D   = pc[(size_t)j * NCAND];     // diagonal word (== v_j)

    u64 s = (v0  & s_bm[0])  | (v1  & s_bm[1])  | (v2  & s_bm[2])  | (v3  & s_bm[3])
          | (v4  & s_bm[4])  | (v5  & s_bm[5])  | (v6  & s_bm[6])  | (v7  & s_bm[7])
          | (v8  & s_bm[8])  | (v9  & s_bm[9])  | (v10 & s_bm[10]) | (v11 & s_bm[11])
          | (v12 & s_bm[12]) | (v13 & s_bm[13]) | (v14 & s_bm[14]) | (v15 & s_bm[15])
          | (v16 & s_bm[16]) | (v17 & s_bm[17]) | (v18 & s_bm[18]) | (v19 & s_bm[19])
          | (v20 & s_bm[20]) | (v21 & s_bm[21]) | (v22 & s_bm[22]) | (v23 & s_bm[23])
          | (v24 & s_bm[24]) | (v25 & s_bm[25]) | (v26 & s_bm[26]) | (v27 & s_bm[27])
          | (v28 & s_bm[28]) | (v29 & s_bm[29]) | (v30 & s_bm[30]) | (v31 & s_bm[31]);

    u64 a = __ballot(s == 0ull);
    u64 supw = 0ull, keepm = 0ull;
    while (a) {
      int k = __ffsll((unsigned long long)a) - 1;
      a &= a - 1ull;
      if (!((supw >> k) & 1ull)) {
        keepm |= 1ull << k;
        if (lane == 0) s_kept[nk] = (u32)(j * 64 + k);
        ++nk;
        if (nk >= POST_NMS) { fin = true; break; }
        supw |= readlane64(D, k);
      }
    }
    if (lane == 0) s_bm[j] = keepm;
    __syncthreads();   // single wave: cheap; orders the s_bm RAW for next chunk
  }

  // ---- phase C: exact fallback past candidate NCAND (unreached on data) ----
  if (nk < POST_NMS) {
    float4 kb[5];
    float  ka[5];
    #pragma unroll
    for (int s = 0; s < 5; ++s) {
      int t = s * 64 + lane;
      float4 v = make_float4(0.f, 0.f, 0.f, 0.f);
      if (t < nk) v = boxes_ws[b * PRE_NMS + s_kept[t]];
      kb[s] = v;
      ka[s] = (v.z - v.x) * (v.w - v.y);
    }
    for (int i = NCAND; i < PRE_NMS; ++i) {
      if (nk >= POST_NMS) break;
      float4 c = boxes_ws[b * PRE_NMS + i];
      float carea = (c.z - c.x) * (c.w - c.y);
      bool over = false;
      #pragma unroll
      for (int s = 0; s < 5; ++s) {
        if (s * 64 < nk) {
          if (s * 64 + lane < nk) {
            float iw = fminf(kb[s].z, c.z) - fmaxf(kb[s].x, c.x);
            float ih = fminf(kb[s].w, c.w) - fmaxf(kb[s].y, c.y);
            iw = fmaxf(iw, 0.0f);
            ih = fmaxf(ih, 0.0f);
            float inter = iw * ih;
            float uni = ka[s] + carea - inter;
            over = over || (inter > 0.7f * fmaxf(uni, 1e-8f));
          }
        }
      }
      if (__ballot((int)over) == 0ull) {
        int s = nk >> 6, l = nk & 63;
        #pragma unroll
        for (int q = 0; q < 5; ++q)
          if (q == s && lane == l) { kb[q] = c; ka[q] = carea; }
        if (lane == 0) s_kept[nk] = (u32)i;
        ++nk;
      }
    }
  }
  __syncthreads();

  // ---- emit: first nk kept (score order), zero-pad to 300 ----
  float4* outv = (float4*)out;
  for (int t = lane; t < POST_NMS; t += 64) {
    float4 v = make_float4(0.f, 0.f, 0.f, 0.f);
    if (t < nk) v = boxes_ws[b * PRE_NMS + s_kept[t]];
    outv[b * POST_NMS + t] = v;
  }
}

// ---------------------------------------------------------------------------
// Fallback: round-1 monolithic kernel (verified) if ws is too small.
// ---------------------------------------------------------------------------
__global__ void __launch_bounds__(NTH)
rpn_proposal_mono(const float* __restrict__ scores,
                  const float* __restrict__ deltas,
                  float* __restrict__ out)
{
  __shared__ __align__(16) char smem[16384 + 32768 + 4096];
  u32* s_hist = (u32*)smem;
  u64* s_cand = (u64*)(smem + 16384);
  u32* s_sfx  = (u32*)(smem + 16384 + 32768);
  float4* s_box = (float4*)smem;
  __shared__ u32 s_kept[POST_NMS];
  __shared__ u32 s_meta[4];

  const int tid = threadIdx.x;
  const int b   = blockIdx.x;
  const float* sc = scores + b * NBOX;

  for (int t = tid; t < NBUCKET; t += NTH) s_hist[t] = 0;
  if (tid < 4) s_meta[tid] = 0;
  __syncthreads();
  for (int m = 0; m < PER; ++m) {
    int i = tid + m * NTH;
    if (i < NBOX) {
      float s = sc[i];
      int bk = (int)(s * (float)NBUCKET);
      bk = bk < 0 ? 0 : (bk > NBUCKET - 1 ? NBUCKET - 1 : bk);
      atomicAdd(&s_hist[bk], 1u);
    }
  }
  __syncthreads();
  {
    u32 g = s_hist[4*tid] + s_hist[4*tid+1] + s_hist[4*tid+2] + s_hist[4*tid+3];
    s_sfx[tid] = g;
  }
  __syncthreads();
  for (int d = 1; d < NTH; d <<= 1) {
    u32 v = (tid + d < NTH) ? s_sfx[tid + d] : 0u;
    __syncthreads();
    s_sfx[tid] += v;
    __syncthreads();
  }
  {
    u32 sg  = s_sfx[tid];
    u32 sgn = (tid < NTH - 1) ? s_sfx[tid + 1] : 0u;
    if (sg >= PRE_NMS && sgn < PRE_NMS) {
      u32 c = sgn;
      for (int t = 4 * tid + 3; t >= 4 * tid; --t) {
        c += s_hist[t];
        if (c >= PRE_NMS) { s_meta[0] = (u32)t; s_meta[1] = c; break; }
      }
    }
  }
  __syncthreads();
  const u32 T = s_meta[0];
  for (int m = 0; m < PER; ++m) {
    int i = tid + m * NTH;
    if (i < NBOX) {
      float s = sc[i];
      int bk = (int)(s * (float)NBUCKET);
      bk = bk < 0 ? 0 : (bk > NBUCKET - 1 ? NBUCKET - 1 : bk);
      if ((u32)bk >= T) {
        u32 pos = atomicAdd(&s_meta[2], 1u);
        if (pos < SEGCAP) {
          u64 key = ((u64)__float_as_uint(s) << 32) | (u32)(~(u32)i);
          s_cand[pos] = key;
        }
      }
    }
  }
  __syncthreads();
  {
    u32 C = s_meta[2]; if (C > SEGCAP) C = SEGCAP;
    for (u32 p = C + tid; p < SEGCAP; p += NTH) s_cand[p] = 0ull;
  }
  for (int kk = 2; kk <= SEGCAP; kk <<= 1) {
    for (int j = kk >> 1; j > 0; j >>= 1) {
      __syncthreads();
      #pragma unroll
      for (int m = 0; m < 2; ++m) {
        int t = tid + m * NTH;
        int i = ((t & ~(j - 1)) << 1) | (t & (j - 1));
        int p = i | j;
        u64 a  = s_cand[i];
        u64 bb = s_cand[p];
        bool desc = (i & kk) == 0;
        bool sw = desc ? (a < bb) : (a > bb);
        if (sw) { s_cand[i] = bb; s_cand[p] = a; }
      }
    }
  }
  __syncthreads();
  const float* dl = deltas + b * (4 * NA * HW);
  float4 bx[3];
  #pragma unroll
  for (int m = 0; m < 3; ++m) {
    int k = tid + m * NTH;
    if (k < PRE_NMS) {
      u64 key = s_cand[k];
      bx[m] = decode_box(dl, (int)(~(u32)key));
    }
  }
  __syncthreads();
  #pragma unroll
  for (int m = 0; m < 3; ++m) {
    int k = tid + m * NTH;
    if (k < PRE_NMS) s_box[k] = bx[m];
  }
  __syncthreads();
  if (tid < 64) {
    const int lane = tid;
    float4 kb[5];
    float  ka[5];
    int nk = 0;
    for (int i = 0; i < PRE_NMS; ++i) {
      if (nk >= POST_NMS) break;
      float4 c = s_box[i];
      float carea = (c.z - c.x) * (c.w - c.y);
      bool over = false;
      #pragma unroll
      for (int s = 0; s < 5; ++s) {
        if (s * 64 < nk) {
          if (s * 64 + lane < nk) {
            float iw = fminf(kb[s].z, c.z) - fmaxf(kb[s].x, c.x);
            float ih = fminf(kb[s].w, c.w) - fmaxf(kb[s].y, c.y);
            iw = fmaxf(iw, 0.0f);
            ih = fmaxf(ih, 0.0f);
            float inter = iw * ih;
            float uni = ka[s] + carea - inter;
            over = over || (inter > 0.7f * fmaxf(uni, 1e-8f));
          }
        }
      }
      if (__ballot((int)over) == 0ull) {
        int s = nk >> 6, l = nk & 63;
        #pragma unroll
        for (int q = 0; q < 5; ++q)
          if (q == s && lane == l) { kb[q] = c; ka[q] = carea; }
        if (lane == 0) s_kept[nk] = (u32)i;
        ++nk;
      }
    }
    if (lane == 0) s_meta[3] = (u32)nk;
  }
  __syncthreads();
  if (tid < POST_NMS) {
    u32 nk = s_meta[3];
    float4 v = make_float4(0.0f, 0.0f, 0.0f, 0.0f);
    if ((u32)tid < nk) v = s_box[s_kept[tid]];
    ((float4*)out)[b * POST_NMS + tid] = v;
  }
}

extern "C" void kernel_launch(void* const* d_in, const int* in_sizes, int n_in,
                              void* d_out, int out_size, void* d_ws, size_t ws_size,
                              hipStream_t stream) {
  const float* scores = (const float*)d_in[0];
  const float* deltas = (const float*)d_in[1];
  (void)in_sizes; (void)n_in; (void)out_size;

  const size_t mask_off   = 196608;                                   // 192KB aligned
  const size_t mask_bytes = (size_t)NB * MWT * NCAND * sizeof(u64);   // 2 MB
  const size_t need       = mask_off + mask_bytes;

  if (ws_size >= need) {
    float4* boxes_ws = (float4*)d_ws;
    u64*    masksT   = (u64*)((char*)d_ws + mask_off);
    topk_rank_decode_kernel<<<dim3(NB), dim3(NTH), 0, stream>>>(scores, deltas, boxes_ws);
    mask_kernel_T<<<dim3(MWT, NCAND / 256, NB), dim3(256), 0, stream>>>(boxes_ws, masksT);
    nms_reduce_kernel<<<dim3(NB), dim3(64), 0, stream>>>(boxes_ws, masksT, (float*)d_out);
  } else {
    rpn_proposal_mono<<<dim3(NB), dim3(NTH), 0, stream>>>(scores, deltas, (float*)d_out);
  }
}